// Round 9
// baseline (724.114 us; speedup 1.0000x reference)
//
#include <hip/hip_runtime.h>
#include <hip/hip_bf16.h>
#include <math.h>

#define N_NODES 65536
#define N_EDGES 262144
#define BATCHSZ 2048
#define F_IN    78
#define K1PAD   96
#define GENES   735
#define GOUT    512
#define HEADS   8
#define HID     64
#define TOT_E   (N_EDGES + N_NODES)   // 327680

typedef unsigned short u16;
typedef unsigned int   u32;
typedef __attribute__((ext_vector_type(4))) float f32x4;
typedef __attribute__((ext_vector_type(8))) short bf16x8;

__device__ __forceinline__ float bf2f(u32 h) {
    u32 u = h << 16;
    return __uint_as_float(u);
}
__device__ __forceinline__ u16 f2bf(float f) {
    u32 u = __float_as_uint(f);
    u32 r = (u + 0x7FFFu + ((u >> 16) & 1u)) >> 16;   // round-to-nearest-even
    return (u16)r;
}

// ================= MFMA bf16 GEMM (node-feature GEMMs) =================
__global__ __launch_bounds__(256) void gemm_mfma(
    const u16* __restrict__ A, const u16* __restrict__ BT, u16* __restrict__ C,
    int M, int N, int K, int ldc)
{
    __shared__ u16 Al[128 * 40];
    __shared__ u16 Bl[128 * 40];
    int t    = threadIdx.x;
    int wid  = t >> 6, lane = t & 63;
    int wm   = wid >> 1, wn = wid & 1;
    int bm   = blockIdx.x * 128, bn = blockIdx.y * 128;

    f32x4 acc[4][4] = {};

    for (int k0 = 0; k0 < K; k0 += 32) {
        #pragma unroll
        for (int i = 0; i < 2; ++i) {
            int flat = t + i * 256;          // 0..511
            int row  = flat >> 2, slot = flat & 3;
            uint4 va = *(const uint4*)(A  + (size_t)(bm + row) * K + k0 + slot * 8);
            *(uint4*)(Al + row * 40 + slot * 8) = va;
            uint4 vb = *(const uint4*)(BT + (size_t)(bn + row) * K + k0 + slot * 8);
            *(uint4*)(Bl + row * 40 + slot * 8) = vb;
        }
        __syncthreads();
        bf16x8 af[4], bfr[4];
        int r0 = wm * 64 + (lane & 15);
        int c0 = wn * 64 + (lane & 15);
        int kk = (lane >> 4) * 8;
        #pragma unroll
        for (int m = 0; m < 4; ++m)
            af[m] = *(const bf16x8*)(Al + (r0 + m * 16) * 40 + kk);
        #pragma unroll
        for (int n = 0; n < 4; ++n)
            bfr[n] = *(const bf16x8*)(Bl + (c0 + n * 16) * 40 + kk);
        #pragma unroll
        for (int m = 0; m < 4; ++m)
            #pragma unroll
            for (int n = 0; n < 4; ++n)
                acc[m][n] = __builtin_amdgcn_mfma_f32_16x16x32_bf16(af[m], bfr[n], acc[m][n], 0, 0, 0);
        __syncthreads();
    }
    int rbase = bm + wm * 64 + (lane >> 4) * 4;
    int cbase = bn + wn * 64 + (lane & 15);
    #pragma unroll
    for (int m = 0; m < 4; ++m)
        #pragma unroll
        for (int n = 0; n < 4; ++n) {
            int col = cbase + n * 16;
            #pragma unroll
            for (int j = 0; j < 4; ++j) {
                int row = rbase + m * 16 + j;
                C[(size_t)row * ldc + col] = f2bf(acc[m][n][j]);
            }
        }
}

// ---- weight/input conversion: f32 -> bf16 (optionally transposed / K-padded) ----
__global__ void conv_x_pad(const float* __restrict__ x, u16* __restrict__ xb) {
    int i = blockIdx.x * 256 + threadIdx.x;          // over N_NODES*K1PAD
    int row = i / K1PAD, col = i - row * K1PAD;
    xb[i] = (col < F_IN) ? f2bf(x[(size_t)row * F_IN + col]) : (u16)0;
}
__global__ void conv_w1t(const float* __restrict__ W, u16* __restrict__ WT) {
    int i = blockIdx.x * 256 + threadIdx.x;          // over GOUT*K1PAD
    int n = i / K1PAD, k = i - n * K1PAD;
    WT[i] = (k < F_IN) ? f2bf(W[(size_t)k * GOUT + n]) : (u16)0;
}
__global__ void conv_w2t(const float* __restrict__ W, u16* __restrict__ WT) {
    int i = blockIdx.x * 256 + threadIdx.x;          // over GOUT*GOUT
    int n = i >> 9, k = i & 511;
    WT[i] = f2bf(W[(size_t)k * GOUT + n]);
}

// ---------------- row-streaming GEMM for tall-skinny MLP layers ----------------
// C[M,N] = A[M,K] @ B[K,N]; A row-major (lda=K), B row-major.
// Block: 256 thr, R = RG*TPC rows staged in LDS; each thread owns RG rows x
// one col-slice (col0 = tid & (N<256 ? N-1 : 255); TPC thread-groups split rows).
// No barrier in K loop; B streams coalesced from L2 (weights <= 1 MB, L2-resident).
// EPI: 2=relu(acc+bias), 3=bn-relu
template<int EPI, int RG, int TPC>
__global__ __launch_bounds__(256) void gemm_rows(
    const float* __restrict__ A, const float* __restrict__ B, float* __restrict__ C,
    int M, int N, int K, int ldc,
    const float* __restrict__ bias,
    const float* __restrict__ bng, const float* __restrict__ bnb,
    const float* __restrict__ bnm, const float* __restrict__ bnv)
{
    extern __shared__ float As[];                 // R * K floats
    const int R = RG * TPC;
    int tid  = threadIdx.x;
    int row0 = blockIdx.x * R;
    for (int r = 0; r < R; ++r)
        for (int k = tid; k < K; k += 256)
            As[r * K + k] = A[(size_t)(row0 + r) * K + k];
    __syncthreads();
    const int effCols = (TPC == 2) ? 128 : 256;
    int col0 = tid & (effCols - 1);
    int rbeg = (TPC == 2) ? (tid >> 7) * RG : 0;
    const float* Ab = As + rbeg * K;
    for (int col = col0; col < N; col += 256) {
        float acc[RG];
        #pragma unroll
        for (int r = 0; r < RG; ++r) acc[r] = 0.f;
        for (int k = 0; k < K; ++k) {
            float b = B[(size_t)k * N + col];
            #pragma unroll
            for (int r = 0; r < RG; ++r)
                acc[r] += Ab[r * K + k] * b;
        }
        #pragma unroll
        for (int r = 0; r < RG; ++r) {
            float v = acc[r];
            if (EPI == 2) { v += bias[col]; v = fmaxf(v, 0.f); }
            if (EPI == 3) {
                float s = bng[col] * rsqrtf(bnv[col] + 1e-5f);
                v = (v + bias[col] - bnm[col]) * s + bnb[col];
                v = fmaxf(v, 0.f);
            }
            C[(size_t)(row0 + rbeg + r) * ldc + col] = v;
        }
    }
}

// ---------------- attention coefficients from bf16 features ----------------
__global__ __launch_bounds__(256) void gat_att(
    const u16* __restrict__ h,
    const float* __restrict__ att_src, const float* __restrict__ att_dst,
    float* __restrict__ aS, float* __restrict__ aD)
{
    int gid  = blockIdx.x * blockDim.x + threadIdx.x;
    int n    = gid >> 6;
    int lane = threadIdx.x & 63;
    if (n >= N_NODES) return;
    int head = lane >> 3;
    int ci   = (lane & 7) * 8;
    uint4 q = *(const uint4*)(h + (size_t)n * GOUT + lane * 8);
    float h0 = bf2f(q.x & 0xffff), h1 = bf2f(q.x >> 16);
    float h2 = bf2f(q.y & 0xffff), h3 = bf2f(q.y >> 16);
    float h4 = bf2f(q.z & 0xffff), h5 = bf2f(q.z >> 16);
    float h6 = bf2f(q.w & 0xffff), h7 = bf2f(q.w >> 16);
    const float* as = att_src + head * HID + ci;
    const float* ad = att_dst + head * HID + ci;
    float ss = h0*as[0] + h1*as[1] + h2*as[2] + h3*as[3]
             + h4*as[4] + h5*as[5] + h6*as[6] + h7*as[7];
    float dd = h0*ad[0] + h1*ad[1] + h2*ad[2] + h3*ad[3]
             + h4*ad[4] + h5*ad[5] + h6*ad[6] + h7*ad[7];
    ss += __shfl_xor(ss, 1); ss += __shfl_xor(ss, 2); ss += __shfl_xor(ss, 4);
    dd += __shfl_xor(dd, 1); dd += __shfl_xor(dd, 2); dd += __shfl_xor(dd, 4);
    if ((lane & 7) == 0) {
        aS[n * HEADS + head] = ss;
        aD[n * HEADS + head] = dd;
    }
}

// ---------------- CSR build ----------------
__global__ void k_init_counts(int* cnt) {
    int i = blockIdx.x * 256 + threadIdx.x;
    if (i < N_NODES) cnt[i] = 1;             // self-loop
}
__global__ void k_count(const int* __restrict__ dst, int* cnt) {
    int e = blockIdx.x * 256 + threadIdx.x;
    if (e < N_EDGES) atomicAdd(&cnt[dst[e]], 1);
}
__global__ void k_scan1(const int* __restrict__ cnt, int* __restrict__ off, int* __restrict__ bsum) {
    __shared__ int s[256];
    int b = blockIdx.x, t = threadIdx.x;
    s[t] = cnt[b * 256 + t]; __syncthreads();
    for (int d = 1; d < 256; d <<= 1) {
        int x = (t >= d) ? s[t - d] : 0;
        __syncthreads();
        s[t] += x;
        __syncthreads();
    }
    off[b * 256 + t + 1] = s[t];
    if (t == 255) bsum[b] = s[255];
}
__global__ void k_scan2(int* bsum) {
    __shared__ int s[256];
    int t = threadIdx.x;
    s[t] = bsum[t]; __syncthreads();
    for (int d = 1; d < 256; d <<= 1) {
        int x = (t >= d) ? s[t - d] : 0;
        __syncthreads();
        s[t] += x;
        __syncthreads();
    }
    bsum[t] = s[t];
}
__global__ void k_scan3(int* __restrict__ off, const int* __restrict__ bsum) {
    int b = blockIdx.x, t = threadIdx.x;
    if (b > 0) off[b * 256 + t + 1] += bsum[b - 1];
    if (b == 0 && t == 0) off[0] = 0;
}
__global__ void k_copy(const int* __restrict__ off, int* __restrict__ cur) {
    int i = blockIdx.x * 256 + threadIdx.x;
    if (i < N_NODES) cur[i] = off[i];
}
__global__ void k_fill(const int* __restrict__ esrc, const int* __restrict__ edst,
                       int* cur, int* __restrict__ srcs, int* __restrict__ dsts) {
    int i = blockIdx.x * 256 + threadIdx.x;
    if (i >= TOT_E) return;
    int s, d;
    if (i < N_EDGES) { s = esrc[i]; d = edst[i]; }
    else             { s = d = i - N_EDGES; }
    int p = atomicAdd(&cur[d], 1);
    srcs[p] = s;
    dsts[p] = d;
}

// ---------------- per-(edge,head) unnormalized attention weight ----------------
__global__ __launch_bounds__(256) void edge_alpha(
    const int* __restrict__ srcs, const int* __restrict__ dsts,
    const float* __restrict__ aS, const float* __restrict__ aD,
    float* __restrict__ ealpha)
{
    int i = blockIdx.x * 256 + threadIdx.x;      // over TOT_E*HEADS
    int o = i >> 3, h = i & 7;
    int s = srcs[o], d = dsts[o];
    float x = aS[s * HEADS + h] + aD[d * HEADS + h];
    x = x > 0.f ? x : 0.2f * x;
    ealpha[i] = expf(x);
}

// ---------------- GAT aggregation: single pass, precomputed weights ----------------
__global__ __launch_bounds__(256) void gat_aggregate(
    const u16* __restrict__ h, const float* __restrict__ ealpha,
    const int* __restrict__ off, const int* __restrict__ srcs,
    const float* __restrict__ bias, u16* __restrict__ out)
{
    int gid  = blockIdx.x * blockDim.x + threadIdx.x;
    int n    = gid >> 6;
    if (n >= N_NODES) return;
    int lane = threadIdx.x & 63;
    int head = lane >> 3;
    int o0 = off[n], o1 = off[n + 1];
    float denom = 0.f;
    float acc[8] = {};
    for (int o = o0; o < o1; ++o) {
        int s = srcs[o];
        float e = ealpha[o * HEADS + head];
        denom += e;
        uint4 q = *(const uint4*)(h + (size_t)s * GOUT + lane * 8);
        acc[0] += e * bf2f(q.x & 0xffff); acc[1] += e * bf2f(q.x >> 16);
        acc[2] += e * bf2f(q.y & 0xffff); acc[3] += e * bf2f(q.y >> 16);
        acc[4] += e * bf2f(q.z & 0xffff); acc[5] += e * bf2f(q.z >> 16);
        acc[6] += e * bf2f(q.w & 0xffff); acc[7] += e * bf2f(q.w >> 16);
    }
    float inv = 1.f / (denom + 1e-16f);
    int c0 = lane * 8;
    float r[8];
    #pragma unroll
    for (int j = 0; j < 8; ++j) {
        float v = acc[j] * inv + bias[c0 + j];
        r[j] = v > 0.f ? v : expm1f(v);
    }
    uint4 w;
    w.x = (u32)f2bf(r[0]) | ((u32)f2bf(r[1]) << 16);
    w.y = (u32)f2bf(r[2]) | ((u32)f2bf(r[3]) << 16);
    w.z = (u32)f2bf(r[4]) | ((u32)f2bf(r[5]) << 16);
    w.w = (u32)f2bf(r[6]) | ((u32)f2bf(r[7]) << 16);
    *(uint4*)(out + (size_t)n * GOUT + c0) = w;
}

// ---------------- global mean pool ----------------
__global__ __launch_bounds__(256) void pool_kernel(
    const u16* __restrict__ x, const int* __restrict__ batch, float* __restrict__ cbuf)
{
    int b = blockIdx.x;
    int lo = 0, hi = N_NODES;
    while (lo < hi) { int mid = (lo + hi) >> 1; if (batch[mid] < b) lo = mid + 1; else hi = mid; }
    int start = lo;
    hi = N_NODES;
    while (lo < hi) { int mid = (lo + hi) >> 1; if (batch[mid] < b + 1) lo = mid + 1; else hi = mid; }
    int end = lo;
    int t = threadIdx.x;
    float s0 = 0.f, s1 = 0.f;
    for (int i = start; i < end; ++i) {
        s0 += bf2f(x[(size_t)i * GOUT + t]);
        s1 += bf2f(x[(size_t)i * GOUT + t + 256]);
    }
    float sc = 1.f / fmaxf((float)(end - start), 1.f);
    cbuf[(size_t)b * 1024 + t]       = s0 * sc;
    cbuf[(size_t)b * 1024 + t + 256] = s1 * sc;
}

// ---------------- final dot ----------------
__global__ __launch_bounds__(64) void final_dot(
    const float* __restrict__ f2, const float* __restrict__ w,
    const float* __restrict__ b, float* __restrict__ out)
{
    int row = blockIdx.x, l = threadIdx.x;
    float v = f2[row * 128 + l] * w[l] + f2[row * 128 + 64 + l] * w[64 + l];
    v += __shfl_xor(v, 32); v += __shfl_xor(v, 16); v += __shfl_xor(v, 8);
    v += __shfl_xor(v, 4);  v += __shfl_xor(v, 2);  v += __shfl_xor(v, 1);
    if (l == 0) out[row] = v + b[0];
}

extern "C" void kernel_launch(void* const* d_in, const int* in_sizes, int n_in,
                              void* d_out, int out_size, void* d_ws, size_t ws_size,
                              hipStream_t stream)
{
    const float* x     = (const float*)d_in[0];
    const int*   ei    = (const int*)  d_in[1];
    const int*   batch = (const int*)  d_in[2];
    const float* x_gen = (const float*)d_in[3];
    const float* W1    = (const float*)d_in[4];
    const float* as1   = (const float*)d_in[5];
    const float* ad1   = (const float*)d_in[6];
    const float* b1    = (const float*)d_in[7];
    const float* W2    = (const float*)d_in[8];
    const float* as2   = (const float*)d_in[9];
    const float* ad2   = (const float*)d_in[10];
    const float* b2    = (const float*)d_in[11];
    const float* gW1   = (const float*)d_in[12];
    const float* gb1   = (const float*)d_in[13];
    const float* bng   = (const float*)d_in[14];
    const float* bnb   = (const float*)d_in[15];
    const float* bnm   = (const float*)d_in[16];
    const float* bnv   = (const float*)d_in[17];
    const float* gW2   = (const float*)d_in[18];
    const float* gb2   = (const float*)d_in[19];
    const float* fW1   = (const float*)d_in[20];
    const float* fb1   = (const float*)d_in[21];
    const float* fW2   = (const float*)d_in[22];
    const float* fb2   = (const float*)d_in[23];
    const float* fW3   = (const float*)d_in[24];
    const float* fb3   = (const float*)d_in[25];
    float* out = (float*)d_out;

    char* ws = (char*)d_ws;
    size_t off_b = 0;
    auto alloc = [&](size_t bytes) -> void* {
        void* p = ws + off_b;
        off_b += (bytes + 255) & ~(size_t)255;
        return p;
    };
    u16*   bufA    = (u16*)  alloc((size_t)N_NODES * GOUT * 2);   // bf16 features
    u16*   bufB    = (u16*)  alloc((size_t)N_NODES * GOUT * 2);   // bf16 features
    u16*   xb      = (u16*)  alloc((size_t)N_NODES * K1PAD * 2);  // x bf16, K-padded
    u16*   w1t     = (u16*)  alloc((size_t)GOUT * K1PAD * 2);     // W1^T bf16 padded
    u16*   w2t     = (u16*)  alloc((size_t)GOUT * GOUT * 2);      // W2^T bf16
    float* aSp     = (float*)alloc((size_t)N_NODES * HEADS * 4);
    float* aDp     = (float*)alloc((size_t)N_NODES * HEADS * 4);
    int*   csr_off = (int*)  alloc((size_t)(N_NODES + 1) * 4);
    int*   csr_cur = (int*)  alloc((size_t)N_NODES * 4);
    int*   bsum    = (int*)  alloc(256 * 4);
    int*   csr_src = (int*)  alloc((size_t)TOT_E * 4);
    int*   csr_dst = (int*)  alloc((size_t)TOT_E * 4);
    float* ealpha  = (float*)alloc((size_t)TOT_E * HEADS * 4);
    float* cbuf    = (float*)alloc((size_t)BATCHSZ * 1024 * 4);   // [g | z]
    float* z1b     = (float*)alloc((size_t)BATCHSZ * 128 * 4);
    float* f1b     = (float*)alloc((size_t)BATCHSZ * 256 * 4);
    float* f2b     = (float*)alloc((size_t)BATCHSZ * 128 * 4);

    if (off_b > ws_size) return;   // clean no-op beats a memory fault

    const int* esrc = ei;
    const int* edst = ei + N_EDGES;

    // ---- conversions (bf16 weights/inputs for MFMA) ----
    conv_x_pad<<<(N_NODES * K1PAD) / 256, 256, 0, stream>>>(x, xb);
    conv_w1t<<<(GOUT * K1PAD) / 256, 256, 0, stream>>>(W1, w1t);
    conv_w2t<<<(GOUT * GOUT) / 256, 256, 0, stream>>>(W2, w2t);

    // ---- CSR by destination ----
    k_init_counts<<<N_NODES / 256, 256, 0, stream>>>(csr_cur);
    k_count<<<N_EDGES / 256, 256, 0, stream>>>(edst, csr_cur);
    k_scan1<<<256, 256, 0, stream>>>(csr_cur, csr_off, bsum);
    k_scan2<<<1, 256, 0, stream>>>(bsum);
    k_scan3<<<256, 256, 0, stream>>>(csr_off, bsum);
    k_copy<<<N_NODES / 256, 256, 0, stream>>>(csr_off, csr_cur);
    k_fill<<<TOT_E / 256, 256, 0, stream>>>(esrc, edst, csr_cur, csr_src, csr_dst);

    // ---- GAT layer 1 (MFMA) ----
    dim3 gMF(N_NODES / 128, GOUT / 128);
    gemm_mfma<<<gMF, 256, 0, stream>>>(xb, w1t, bufA, N_NODES, GOUT, K1PAD, GOUT);
    gat_att<<<N_NODES / 4, 256, 0, stream>>>(bufA, as1, ad1, aSp, aDp);
    edge_alpha<<<(TOT_E * HEADS) / 256, 256, 0, stream>>>(csr_src, csr_dst, aSp, aDp, ealpha);
    gat_aggregate<<<N_NODES / 4, 256, 0, stream>>>(bufA, ealpha, csr_off, csr_src, b1, bufB);

    // ---- GAT layer 2 (MFMA) ----
    gemm_mfma<<<gMF, 256, 0, stream>>>(bufB, w2t, bufA, N_NODES, GOUT, GOUT, GOUT);
    gat_att<<<N_NODES / 4, 256, 0, stream>>>(bufA, as2, ad2, aSp, aDp);
    edge_alpha<<<(TOT_E * HEADS) / 256, 256, 0, stream>>>(csr_src, csr_dst, aSp, aDp, ealpha);
    gat_aggregate<<<N_NODES / 4, 256, 0, stream>>>(bufA, ealpha, csr_off, csr_src, b2, bufB);

    // ---- pool ----
    pool_kernel<<<BATCHSZ, 256, 0, stream>>>(bufB, batch, cbuf);

    // ---- genomic encoder: row-streaming GEMMs ----
    // gG1: M=2048,N=128,K=735  -> RG=1,TPC=2 (R=2), grid 1024, LDS 2*735*4
    gemm_rows<3,1,2><<<BATCHSZ/2, 256, 2*GENES*4, stream>>>(
        x_gen, gW1, z1b, BATCHSZ, 128, GENES, 128, gb1, bng, bnb, bnm, bnv);
    // gG2: M=2048,N=512,K=128  -> RG=4,TPC=1 (R=4), grid 512, LDS 4*128*4
    gemm_rows<2,4,1><<<BATCHSZ/4, 256, 4*128*4, stream>>>(
        z1b, gW2, cbuf + 512, BATCHSZ, GOUT, 128, 1024, gb2, nullptr, nullptr, nullptr, nullptr);

    // ---- fusion MLP: row-streaming GEMMs ----
    // gF1: M=2048,N=256,K=1024 -> RG=4,TPC=1 (R=4), grid 512, LDS 4*1024*4
    gemm_rows<2,4,1><<<BATCHSZ/4, 256, 4*1024*4, stream>>>(
        cbuf, fW1, f1b, BATCHSZ, 256, 1024, 256, fb1, nullptr, nullptr, nullptr, nullptr);
    // gF2: M=2048,N=128,K=256  -> RG=1,TPC=2 (R=2), grid 1024, LDS 2*256*4
    gemm_rows<2,1,2><<<BATCHSZ/2, 256, 2*256*4, stream>>>(
        f1b, fW2, f2b, BATCHSZ, 128, 256, 128, fb2, nullptr, nullptr, nullptr, nullptr);
    final_dot<<<BATCHSZ, 64, 0, stream>>>(f2b, fW3, fb3, out);
}